// Round 7
// baseline (223.416 us; speedup 1.0000x reference)
//
#include <hip/hip_runtime.h>

// Causal MHA forward, B=4 H=16 S=2048 D=64, fp32 I/O, bf16 MFMA compute.
// R11: amortize per-sync-region overhead.  Evidence chain: R9 (2x occupancy,
// null) + R10 (pinned prefetch, null) + tiny conflict/HBM numbers exclude
// latency-exposure, occupancy, banks, and BW.  Remaining: all 8 waves are
// barrier-locked into the same phase each tile -> dep-chain stalls are
// CORRELATED across waves (m233 mechanism); ~3700 cyc/tile of sync-region
// overhead on ~2000 cyc of work.  Single-variable fix: BK 64->128 (2x work
// per sync region, 18 tiles/WG instead of 36, half the barriers), staging
// payload 32 VGPRs still pinned via asm loads + dataflow-ordered waitcnt.
// V^T stride 136 (same dword residue mod 32 as R7's 72 -> preserves the
// proven 2-way-free bank pattern for staging writes and fragment reads).
// Everything else R10-verbatim: mfma_f32_32x32x16_bf16, 8 waves x 32-row
// strips (BQ=256), in-register P via pk2 + v_permlane32_swap_b32, in-lane
// denominator tree + permlane/bpermute epilogue, double-buffered K/V LDS,
// one barrier per tile, no-max flash softmax (exp2, log2e folded into Q
// scale), 256 WGs with bid%8==bh%8 XCD co-location.

typedef float  f32x4   __attribute__((ext_vector_type(4)));
typedef float  f32x16  __attribute__((ext_vector_type(16)));
typedef short  bf16x8  __attribute__((ext_vector_type(8)));

#define NH      16
#define DH      64
#define SEQ     2048
#define NSTATE  1024
#define ROW3    3072
#define BQ      256
#define BK      128
#define NQB     (SEQ / BQ)      // 8 q-blocks of 256
#define KST     72              // K[kv][d] d-stride (shorts)
#define VST     136             // V^T[d][kv] kv-stride (shorts), 128 kv + 8 pad
#define NEG_BIG (-1e9f)
#define QSC     (0.125f * 1.4426950408889634f)   // 1/sqrt(64) * log2(e)

// pack two fp32 -> two RNE bf16 in one u32
static __device__ __forceinline__ unsigned pk2(float x, float y) {
    unsigned ux = __builtin_bit_cast(unsigned, x);
    unsigned uy = __builtin_bit_cast(unsigned, y);
    ux += 0x7FFFu + ((ux >> 16) & 1u);
    uy += 0x7FFFu + ((uy >> 16) & 1u);
    return __builtin_amdgcn_perm(uy, ux, 0x07060302u);   // [uy.hi16 : ux.hi16]
}

// pinned global loads: issue point fixed by asm volatile ordering
#define GLOAD4(dst, ptr) \
    __asm__ volatile("global_load_dwordx4 %0, %1, off" : "=v"(dst) : "v"(ptr))
#define GLOAD1(dst, ptr) \
    __asm__ volatile("global_load_dword %0, %1, off" : "=v"(dst) : "v"(ptr))

// wait for the staged payload; "+v" operands create the dataflow edge that
// keeps consumers (pk2 -> LDS writes) AFTER the wait and payload live above it
#define STAGE_WAIT()                                                           \
    __asm__ volatile("s_waitcnt vmcnt(0)"                                      \
        : "+v"(kp[0]), "+v"(kp[1]), "+v"(kp[2]), "+v"(kp[3]),                  \
          "+v"(vp[0]),  "+v"(vp[1]),  "+v"(vp[2]),  "+v"(vp[3]),               \
          "+v"(vp[4]),  "+v"(vp[5]),  "+v"(vp[6]),  "+v"(vp[7]),               \
          "+v"(vp[8]),  "+v"(vp[9]),  "+v"(vp[10]), "+v"(vp[11]),              \
          "+v"(vp[12]), "+v"(vp[13]), "+v"(vp[14]), "+v"(vp[15])               \
        :: "memory")

// ---- staging: issue global loads into regs (no wait) --------------------
// K: 128kv x 64d fp32, float4 slots: p=tid+512i (i<4), kv=p>>4, d=4*(p&15).
// V: two 64-kv sub-tiles; per sub, R7 scheme: d=(tid&15)+16i, kv=2*(tid>>4)
//    + 64*sub; scalar row-pairs (kv, kv+1) at col d.
#define ISSUE_STAGE(KV0)                                                       \
    {                                                                          \
        _Pragma("unroll")                                                      \
        for (int i = 0; i < 4; ++i) {                                          \
            int p  = tid + 512 * i;                                            \
            int kv = p >> 4;                                                   \
            int d  = (p & 15) * 4;                                             \
            const float* gp = kbase + (size_t)((KV0) + kv) * ROW3 + d;         \
            GLOAD4(kp[i], gp);                                                 \
        }                                                                      \
        _Pragma("unroll")                                                      \
        for (int sub = 0; sub < 2; ++sub) {                                    \
            _Pragma("unroll")                                                  \
            for (int i = 0; i < 4; ++i) {                                      \
                int d  = (tid & 15) + 16 * i;                                  \
                int kv = (tid >> 4) * 2 + 64 * sub;                            \
                const float* gp = vbase + (size_t)((KV0) + kv) * ROW3 + d;     \
                GLOAD1(vp[8 * sub + 2 * i],     gp);                           \
                GLOAD1(vp[8 * sub + 2 * i + 1], gp + ROW3);                    \
            }                                                                  \
        }                                                                      \
    }

// ---- staging: convert waited payload -> bf16 LDS tile -------------------
#define COMMIT_STAGE(BUF)                                                      \
    {                                                                          \
        _Pragma("unroll")                                                      \
        for (int i = 0; i < 4; ++i) {                                          \
            int p  = tid + 512 * i;                                            \
            int kv = p >> 4;                                                   \
            int d  = (p & 15) * 4;                                             \
            uint2 w;                                                           \
            w.x = pk2(kp[i][0], kp[i][1]);                                     \
            w.y = pk2(kp[i][2], kp[i][3]);                                     \
            *(uint2*)&Klds[BUF][kv * KST + d] = w;                             \
        }                                                                      \
        _Pragma("unroll")                                                      \
        for (int sub = 0; sub < 2; ++sub) {                                    \
            _Pragma("unroll")                                                  \
            for (int i = 0; i < 4; ++i) {                                      \
                int d  = (tid & 15) + 16 * i;                                  \
                int kv = (tid >> 4) * 2 + 64 * sub;                            \
                *(unsigned*)&Vlds[BUF][d * VST + kv] =                         \
                    pk2(vp[8 * sub + 2 * i], vp[8 * sub + 2 * i + 1]);         \
            }                                                                  \
        }                                                                      \
    }

__global__ __launch_bounds__(512, 2)
void mha_fwd(const float* __restrict__ x, float* __restrict__ out) {
    const int tid  = threadIdx.x;
    const int wave = tid >> 6;        // 0..7 : one 32-row q strip each
    const int lane = tid & 63;
    const int r31  = lane & 31;       // MFMA row/col lane index
    const int hl   = lane >> 5;       // lane half

    const int bid = blockIdx.x;       // 0..255 ; bid%8 == bh%8 -> XCD co-location
    const int pr  = bid >> 6;         // pair index 0..3
    const int bh  = bid & 63;
    const int b   = bh >> 4;
    const int h   = bh & 15;

    const float* xb    = x + (size_t)b * SEQ * ROW3;
    const float* kbase = xb + NSTATE + h * DH;
    const float* vbase = xb + 2 * NSTATE + h * DH;
    float*       ob    = out + (size_t)b * SEQ * NSTATE + h * DH;

    __shared__ __align__(16) short Klds[2][BK * KST];    // K[kv][d]   bf16, dbuf (36.9 KB)
    __shared__ __align__(16) short Vlds[2][DH * VST];    // V^T[d][kv] bf16, dbuf (34.8 KB)

    // prefetch payload (live across one compute tile)
    f32x4 kp[4];
    float vp[16];

#pragma unroll 1
    for (int ph = 0; ph < 2; ++ph) {
        const int qblk   = ph ? (NQB - 1 - pr) : pr;     // pair (i, 7-i): 18 tiles
        const int q0     = qblk * BQ;
        const int qstrip = q0 + wave * 32;
        const int qrow   = qstrip + r31;                 // this lane's q (col of S^T)

        // ---- Q fragments (B-operand of S^T), 4 k-chunks, scaled by QSC ----
        bf16x8 qf[4];
        {
            const float* qp = xb + (size_t)qrow * ROW3 + h * DH + hl * 8;
#pragma unroll
            for (int kc = 0; kc < 4; ++kc) {
                f32x4 a = *(const f32x4*)(qp + 16 * kc);
                f32x4 c = *(const f32x4*)(qp + 16 * kc + 4);
                union { bf16x8 v; unsigned u[4]; } qq;
                qq.u[0] = pk2(a[0] * QSC, a[1] * QSC);
                qq.u[1] = pk2(a[2] * QSC, a[3] * QSC);
                qq.u[2] = pk2(c[0] * QSC, c[1] * QSC);
                qq.u[3] = pk2(c[2] * QSC, c[3] * QSC);
                qf[kc] = qq.v;
            }
        }

        f32x16 o0, o1;                 // O[q 32][d 0..31], [d 32..63]
#pragma unroll
        for (int r = 0; r < 16; ++r) { o0[r] = 0.f; o1[r] = 0.f; }
        float dl = 0.f;                // per-lane softmax denominator (q = r31)

        const int ntiles = q0 / BK + BQ / BK;

        __syncthreads();               // protect LDS reuse from previous phase
        ISSUE_STAGE(0)
        STAGE_WAIT();
        COMMIT_STAGE(0)
        __syncthreads();

#pragma unroll 1
        for (int it = 0; it < ntiles; ++it) {
            const int kv0 = it * BK;
            const int cur = it & 1;
            const bool pf = (it + 1 < ntiles);

            // pinned issue of next tile's loads: latency hides under compute
            if (pf) ISSUE_STAGE((it + 1) * BK)

            if (kv0 <= qstrip + 31) {          // strip not fully masked
#pragma unroll
                for (int H = 0; H < 4; ++H) {  // four 32-kv halves
                    const int kvb = kv0 + 32 * H;
                    if (kvb <= qstrip + 31) {  // half not fully masked (uniform)
                        // K fragments (A): row kv = 32H + r31, k = 16kc + 8hl + j
                        bf16x8 kf[4];
#pragma unroll
                        for (int kc = 0; kc < 4; ++kc)
                            kf[kc] = *(const bf16x8*)&Klds[cur][(32 * H + r31) * KST + 16 * kc + 8 * hl];

                        // S^T half tile: 32kv x 32q, accumulated over k
                        f32x16 s;
#pragma unroll
                        for (int r = 0; r < 16; ++r) s[r] = 0.f;
#pragma unroll
                        for (int kc = 0; kc < 4; ++kc)
                            s = __builtin_amdgcn_mfma_f32_32x32x16_bf16(kf[kc], qf[kc], s, 0, 0, 0);

                        if (kvb + 31 > qstrip) {          // crosses diagonal
#pragma unroll
                            for (int r = 0; r < 16; ++r) {
                                int kvg = kvb + (r & 3) + 8 * (r >> 2) + 4 * hl;
                                if (kvg > qrow) s[r] = NEG_BIG;
                            }
                        }
#pragma unroll
                        for (int r = 0; r < 16; ++r)
                            s[r] = __builtin_amdgcn_exp2f(s[r]);

                        // denominator: tree sum (masked elems are 0)
                        {
                            float a0 = (s[0] + s[1]) + (s[2] + s[3]);
                            float a1 = (s[4] + s[5]) + (s[6] + s[7]);
                            float a2 = (s[8] + s[9]) + (s[10] + s[11]);
                            float a3 = (s[12] + s[13]) + (s[14] + s[15]);
                            dl += (a0 + a1) + (a2 + a3);
                        }

                        // P -> bf16 A-fragments in-register (2 chunks of 16 kv)
#pragma unroll
                        for (int cc = 0; cc < 2; ++cc) {
                            unsigned wA = pk2(s[8 * cc + 0], s[8 * cc + 1]);
                            unsigned wB = pk2(s[8 * cc + 2], s[8 * cc + 3]);
                            unsigned wC = pk2(s[8 * cc + 4], s[8 * cc + 5]);
                            unsigned wD = pk2(s[8 * cc + 6], s[8 * cc + 7]);
                            // swap hi-lanes of first with lo-lanes of second:
                            // (wA,wC) -> (j01, j45); (wB,wD) -> (j23, j67)
                            __asm__ volatile("v_permlane32_swap_b32 %0, %1"
                                             : "+v"(wA), "+v"(wC));
                            __asm__ volatile("v_permlane32_swap_b32 %0, %1"
                                             : "+v"(wB), "+v"(wD));
                            union { bf16x8 v; unsigned u[4]; } pa;
                            pa.u[0] = wA; pa.u[1] = wB; pa.u[2] = wC; pa.u[3] = wD;

                            const int c = 2 * H + cc;     // kv chunk in tile (0..7)
                            bf16x8 vf0 = *(const bf16x8*)&Vlds[cur][(r31)      * VST + 16 * c + 8 * hl];
                            bf16x8 vf1 = *(const bf16x8*)&Vlds[cur][(32 + r31) * VST + 16 * c + 8 * hl];
                            o0 = __builtin_amdgcn_mfma_f32_32x32x16_bf16(pa.v, vf0, o0, 0, 0, 0);
                            o1 = __builtin_amdgcn_mfma_f32_32x32x16_bf16(pa.v, vf1, o1, 0, 0, 0);
                        }
                    }
                }
            }

            if (pf) { STAGE_WAIT(); COMMIT_STAGE(cur ^ 1) }
            __syncthreads();
        }

        // ---- epilogue ----
        // cross-half denominator: dl_total(q) = dl[lane q] + dl[lane q^32]
        {
            unsigned da = __builtin_bit_cast(unsigned, dl);
            unsigned db = da;
            __asm__ volatile("v_permlane32_swap_b32 %0, %1" : "+v"(da), "+v"(db));
            float dtot = __builtin_bit_cast(float, da) + __builtin_bit_cast(float, db);
            float rcp  = 1.0f / dtot;              // valid in all lanes for q=r31
#pragma unroll
            for (int r = 0; r < 16; ++r) {
                int srcq = (r & 3) + 8 * (r >> 2) + 4 * hl;   // O row for reg r
                float lr = __builtin_bit_cast(float,
                    __builtin_amdgcn_ds_bpermute(srcq << 2,
                        __builtin_bit_cast(int, rcp)));
                const size_t row = (size_t)(qstrip + srcq) * NSTATE;
                ob[row + r31]      = o0[r] * lr;
                ob[row + 32 + r31] = o1[r] * lr;
            }
        }
    }
}

extern "C" void kernel_launch(void* const* d_in, const int* in_sizes, int n_in,
                              void* d_out, int out_size, void* d_ws, size_t ws_size,
                              hipStream_t stream) {
    const float* x = (const float*)d_in[0];   // [B,S,3*NSTATE] fp32
    // d_in[1] (attn_mask) is not read: the mask is causal and computed inline.
    float* out = (float*)d_out;               // [B,S,NSTATE] fp32
    dim3 grid(4 * NH * (NQB / 2));            // 256 WGs, 1D (bid%8 == bh%8)
    dim3 block(512);
    hipLaunchKernelGGL(mha_fwd, grid, block, 0, stream, x, out);
}

// Round 10
// 215.961 us; speedup vs baseline: 1.0345x; 1.0345x over previous
//
#include <hip/hip_runtime.h>
#include <hip/hip_bf16.h>

// Causal MHA forward, B=4 H=16 S=2048 D=64, fp32 I/O, bf16 MFMA compute.
// R14 == R13 with the compile fix: __hip_bfloat162 is not trivially copyable
// on this ROCm, so the bit_cast in pk2 becomes __builtin_memcpy (identical
// codegen).  R13 rationale: R12 failed post-timing because the R10 asm-load
// pinning (asm volatile global_load + dataflow waitcnt) lets the compiler
// copy/spill a load's dst register BEFORE the wait -> timing-sensitive race.
// R10 proved pinning perf-neutral, so all asm staging machinery is removed:
// plain C++ loads (R7 semantics, compiler-managed waitcnts).  The R11
// calibration (VALU issue ~= MFMA issue, software pk2 = 6 VALU ops dominating)
// is addressed safely: pk2 -> __float22bfloat162_rn, one v_cvt_pk_bf16_f32
// (m240: compiler casts beat hand-written cvt asm, no ordering hazards).
// Everything else R7-verbatim: mfma_f32_32x32x16_bf16, 8 waves x 32-row
// strips (BQ=256, BK=64), in-register P via cvt_pk + v_permlane32_swap_b32,
// in-lane denominator tree + permlane/bpermute epilogue, double-buffered
// K/V LDS, one barrier per tile, no-max flash softmax (exp2, log2e folded
// into Q scale), stride-72 layouts, 256 WGs with bid%8==bh%8 XCD co-location,
// 2-way-free V transpose staging.

typedef float  f32x4   __attribute__((ext_vector_type(4)));
typedef float  f32x16  __attribute__((ext_vector_type(16)));
typedef short  bf16x8  __attribute__((ext_vector_type(8)));

#define NH      16
#define DH      64
#define SEQ     2048
#define NSTATE  1024
#define ROW3    3072
#define BQ      256
#define BK      64
#define NQB     (SEQ / BQ)      // 8 q-blocks of 256
#define KST     72
#define VST     72
#define NEG_BIG (-1e9f)
#define QSC     (0.125f * 1.4426950408889634f)   // 1/sqrt(64) * log2(e)

// pack two fp32 -> two RNE bf16 in one u32 (low16 = bf16(x), high16 = bf16(y))
// Lowers to a single v_cvt_pk_bf16_f32 on gfx950 (compiler-scheduled, no asm).
static __device__ __forceinline__ unsigned pk2(float x, float y) {
    float2 f2; f2.x = x; f2.y = y;
    __hip_bfloat162 b = __float22bfloat162_rn(f2);
    unsigned r;
    __builtin_memcpy(&r, &b, 4);
    return r;
}

// ---- staging: issue global loads into regs (no wait) --------------------
// K: 64kv x 64d fp32, thread slots kv=p>>4, d=4*(p&15), 2 iters (float4).
// V: d=(tid&15)+16i, kv=2*(tid>>4): rows kv,kv+1 at col d (scalar pairs).
#define ISSUE_STAGE(KV0)                                                       \
    {                                                                          \
        _Pragma("unroll")                                                      \
        for (int i = 0; i < 2; ++i) {                                          \
            int p  = tid + 512 * i;                                            \
            int kv = p >> 4;                                                   \
            int d  = (p & 15) * 4;                                             \
            kp[i] = *(const f32x4*)(kbase + (size_t)((KV0) + kv) * ROW3 + d);  \
        }                                                                      \
        _Pragma("unroll")                                                      \
        for (int i = 0; i < 4; ++i) {                                          \
            int d  = (tid & 15) + 16 * i;                                      \
            int kv = (tid >> 4) * 2;                                           \
            const float* gp = vbase + (size_t)((KV0) + kv) * ROW3 + d;         \
            vp[2 * i]     = gp[0];                                             \
            vp[2 * i + 1] = gp[ROW3];                                          \
        }                                                                      \
    }

// ---- staging: convert prefetched regs -> bf16 LDS tile ------------------
#define COMMIT_STAGE(BUF)                                                      \
    {                                                                          \
        _Pragma("unroll")                                                      \
        for (int i = 0; i < 2; ++i) {                                          \
            int p  = tid + 512 * i;                                            \
            int kv = p >> 4;                                                   \
            int d  = (p & 15) * 4;                                             \
            uint2 w;                                                           \
            w.x = pk2(kp[i][0], kp[i][1]);                                     \
            w.y = pk2(kp[i][2], kp[i][3]);                                     \
            *(uint2*)&Klds[BUF][kv * KST + d] = w;                             \
        }                                                                      \
        _Pragma("unroll")                                                      \
        for (int i = 0; i < 4; ++i) {                                          \
            int d  = (tid & 15) + 16 * i;                                      \
            int kv = (tid >> 4) * 2;                                           \
            *(unsigned*)&Vlds[BUF][d * VST + kv] = pk2(vp[2 * i], vp[2 * i + 1]); \
        }                                                                      \
    }

__global__ __launch_bounds__(512, 2)
void mha_fwd(const float* __restrict__ x, float* __restrict__ out) {
    const int tid  = threadIdx.x;
    const int wave = tid >> 6;        // 0..7 : one 32-row q strip each
    const int lane = tid & 63;
    const int r31  = lane & 31;       // MFMA row/col lane index
    const int hl   = lane >> 5;       // lane half

    const int bid = blockIdx.x;       // 0..255 ; bid%8 == bh%8 -> XCD co-location
    const int pr  = bid >> 6;         // pair index 0..3
    const int bh  = bid & 63;
    const int b   = bh >> 4;
    const int h   = bh & 15;

    const float* xb    = x + (size_t)b * SEQ * ROW3;
    const float* kbase = xb + NSTATE + h * DH;
    const float* vbase = xb + 2 * NSTATE + h * DH;
    float*       ob    = out + (size_t)b * SEQ * NSTATE + h * DH;

    __shared__ __align__(16) short Klds[2][BK * KST];    // K[kv][d]   bf16, dbuf
    __shared__ __align__(16) short Vlds[2][DH * VST];    // V^T[d][kv] bf16, dbuf

    // prefetch registers
    f32x4 kp[2];
    float vp[8];

#pragma unroll 1
    for (int ph = 0; ph < 2; ++ph) {
        const int qblk   = ph ? (NQB - 1 - pr) : pr;     // pair (i, 7-i): 36 tiles
        const int q0     = qblk * BQ;
        const int qstrip = q0 + wave * 32;
        const int qrow   = qstrip + r31;                 // this lane's q (col of S^T)

        // ---- Q fragments (B-operand of S^T), 4 k-chunks, scaled by QSC ----
        bf16x8 qf[4];
        {
            const float* qp = xb + (size_t)qrow * ROW3 + h * DH + hl * 8;
#pragma unroll
            for (int kc = 0; kc < 4; ++kc) {
                f32x4 a = *(const f32x4*)(qp + 16 * kc);
                f32x4 c = *(const f32x4*)(qp + 16 * kc + 4);
                union { bf16x8 v; unsigned u[4]; } qq;
                qq.u[0] = pk2(a[0] * QSC, a[1] * QSC);
                qq.u[1] = pk2(a[2] * QSC, a[3] * QSC);
                qq.u[2] = pk2(c[0] * QSC, c[1] * QSC);
                qq.u[3] = pk2(c[2] * QSC, c[3] * QSC);
                qf[kc] = qq.v;
            }
        }

        f32x16 o0, o1;                 // O[q 32][d 0..31], [d 32..63]
#pragma unroll
        for (int r = 0; r < 16; ++r) { o0[r] = 0.f; o1[r] = 0.f; }
        float dl = 0.f;                // per-lane softmax denominator (q = r31)

        const int ntiles = q0 / BK + BQ / BK;

        __syncthreads();               // protect LDS reuse from previous phase
        ISSUE_STAGE(0)
        COMMIT_STAGE(0)
        __syncthreads();

#pragma unroll 1
        for (int it = 0; it < ntiles; ++it) {
            const int kv0 = it * BK;
            const int cur = it & 1;
            const bool pf = (it + 1 < ntiles);

            // issue next tile's global loads early; latency hides under compute
            if (pf) ISSUE_STAGE((it + 1) * BK)

            if (kv0 <= qstrip + 31) {          // strip not fully masked
#pragma unroll
                for (int H = 0; H < 2; ++H) {  // two 32-kv halves
                    const int kvb = kv0 + 32 * H;
                    if (kvb <= qstrip + 31) {  // half not fully masked (uniform)
                        // K fragments (A): row kv = r31, k = 16kc + 8hl + j
                        bf16x8 kf[4];
#pragma unroll
                        for (int kc = 0; kc < 4; ++kc)
                            kf[kc] = *(const bf16x8*)&Klds[cur][(32 * H + r31) * KST + 16 * kc + 8 * hl];

                        // S^T half tile: 32kv x 32q, accumulated over k
                        f32x16 s;
#pragma unroll
                        for (int r = 0; r < 16; ++r) s[r] = 0.f;
#pragma unroll
                        for (int kc = 0; kc < 4; ++kc)
                            s = __builtin_amdgcn_mfma_f32_32x32x16_bf16(kf[kc], qf[kc], s, 0, 0, 0);

                        if (kvb + 31 > qstrip) {          // crosses diagonal
#pragma unroll
                            for (int r = 0; r < 16; ++r) {
                                int kvg = kvb + (r & 3) + 8 * (r >> 2) + 4 * hl;
                                if (kvg > qrow) s[r] = NEG_BIG;
                            }
                        }
#pragma unroll
                        for (int r = 0; r < 16; ++r)
                            s[r] = __builtin_amdgcn_exp2f(s[r]);

                        // denominator: tree sum (masked elems are 0)
                        {
                            float a0 = (s[0] + s[1]) + (s[2] + s[3]);
                            float a1 = (s[4] + s[5]) + (s[6] + s[7]);
                            float a2 = (s[8] + s[9]) + (s[10] + s[11]);
                            float a3 = (s[12] + s[13]) + (s[14] + s[15]);
                            dl += (a0 + a1) + (a2 + a3);
                        }

                        // P -> bf16 A-fragments in-register (2 chunks of 16 kv)
#pragma unroll
                        for (int cc = 0; cc < 2; ++cc) {
                            unsigned wA = pk2(s[8 * cc + 0], s[8 * cc + 1]);
                            unsigned wB = pk2(s[8 * cc + 2], s[8 * cc + 3]);
                            unsigned wC = pk2(s[8 * cc + 4], s[8 * cc + 5]);
                            unsigned wD = pk2(s[8 * cc + 6], s[8 * cc + 7]);
                            // swap hi-lanes of first with lo-lanes of second:
                            // (wA,wC) -> (j01, j45); (wB,wD) -> (j23, j67)
                            __asm__ volatile("v_permlane32_swap_b32 %0, %1"
                                             : "+v"(wA), "+v"(wC));
                            __asm__ volatile("v_permlane32_swap_b32 %0, %1"
                                             : "+v"(wB), "+v"(wD));
                            union { bf16x8 v; unsigned u[4]; } pa;
                            pa.u[0] = wA; pa.u[1] = wB; pa.u[2] = wC; pa.u[3] = wD;

                            const int c = 2 * H + cc;     // global kv chunk
                            bf16x8 vf0 = *(const bf16x8*)&Vlds[cur][(r31)      * VST + 16 * c + 8 * hl];
                            bf16x8 vf1 = *(const bf16x8*)&Vlds[cur][(32 + r31) * VST + 16 * c + 8 * hl];
                            o0 = __builtin_amdgcn_mfma_f32_32x32x16_bf16(pa.v, vf0, o0, 0, 0, 0);
                            o1 = __builtin_amdgcn_mfma_f32_32x32x16_bf16(pa.v, vf1, o1, 0, 0, 0);
                        }
                    }
                }
            }

            if (pf) COMMIT_STAGE(cur ^ 1)
            __syncthreads();
        }

        // ---- epilogue ----
        // cross-half denominator: dl_total(q) = dl[lane q] + dl[lane q^32]
        {
            unsigned da = __builtin_bit_cast(unsigned, dl);
            unsigned db = da;
            __asm__ volatile("v_permlane32_swap_b32 %0, %1" : "+v"(da), "+v"(db));
            float dtot = __builtin_bit_cast(float, da) + __builtin_bit_cast(float, db);
            float rcp  = 1.0f / dtot;              // valid in all lanes for q=r31
#pragma unroll
            for (int r = 0; r < 16; ++r) {
                int srcq = (r & 3) + 8 * (r >> 2) + 4 * hl;   // O row for reg r
                float lr = __builtin_bit_cast(float,
                    __builtin_amdgcn_ds_bpermute(srcq << 2,
                        __builtin_bit_cast(int, rcp)));
                const size_t row = (size_t)(qstrip + srcq) * NSTATE;
                ob[row + r31]      = o0[r] * lr;
                ob[row + 32 + r31] = o1[r] * lr;
            }
        }
    }
}

extern "C" void kernel_launch(void* const* d_in, const int* in_sizes, int n_in,
                              void* d_out, int out_size, void* d_ws, size_t ws_size,
                              hipStream_t stream) {
    const float* x = (const float*)d_in[0];   // [B,S,3*NSTATE] fp32
    // d_in[1] (attn_mask) is not read: the mask is causal and computed inline.
    float* out = (float*)d_out;               // [B,S,NSTATE] fp32
    dim3 grid(4 * NH * (NQB / 2));            // 256 WGs, 1D (bid%8 == bh%8)
    dim3 block(512);
    hipLaunchKernelGGL(mha_fwd, grid, block, 0, stream, x, out);
}